// Round 2
// baseline (369.057 us; speedup 1.0000x reference)
//
#include <hip/hip_runtime.h>
#include <stdint.h>
#include <math.h>

// ---------------------------------------------------------------------------
// Generator_44555990728950. B=4096 molecules, N=32 nodes (chain), H=128,
// 16 GAT layers. All 32 nodes of a molecule are identical through the GAT
// stack (broadcast init + attention weights sum to 1 over identical
// neighbors), so: layer = relu(x + x@W + b), one class per molecule.
// R8 restructure: BARRIER-FREE, one molecule per wave.
//   - 4096 independent waves (1024 blocks x 4 waves) = the 50% occupancy cap
//     given by problem size; zero __syncthreads() anywhere (was 32 block-wide
//     barriers -> convoy stalls, VALUBusy 42%).
//   - prologue kernel pre-converts w1+gat_w fp32 -> fp64 into d_ws (2.23 MB,
//     L2-resident): main loop is pure {ds_read_b128 broadcast of x, 16B
//     coalesced W load, 2 dfma} -- no cvt tax (was 2 cvt per 4 dfma).
//   - fallback variant (cvt in loop) if ws_size is too small.
// Deterministic pipeline fp64; JAX partitionable threefry bit-exact; outputs
// fp32. Per-node sampling / edge heads unchanged.
// ---------------------------------------------------------------------------

struct U2 { uint32_t a, b; };

// Threefry-2x32, 20 rounds, exactly as jax._src.prng
__device__ __forceinline__ U2 threefry(uint32_t k0, uint32_t k1, uint32_t x0, uint32_t x1) {
  const uint32_t ks2 = k0 ^ k1 ^ 0x1BD11BDAu;
#define TFR(r) { x0 += x1; x1 = (x1 << (r)) | (x1 >> (32 - (r))); x1 ^= x0; }
  x0 += k0;  x1 += k1;
  TFR(13) TFR(15) TFR(26) TFR(6)
  x0 += k1;  x1 += ks2 + 1u;
  TFR(17) TFR(29) TFR(16) TFR(24)
  x0 += ks2; x1 += k0 + 2u;
  TFR(13) TFR(15) TFR(26) TFR(6)
  x0 += k0;  x1 += k1 + 3u;
  TFR(17) TFR(29) TFR(16) TFR(24)
  x0 += k1;  x1 += ks2 + 4u;
  TFR(13) TFR(15) TFR(26) TFR(6)
  x0 += ks2; x1 += k0 + 5u;
#undef TFR
  U2 r; r.a = x0; r.b = x1; return r;
}

// partitionable random_bits, 32-bit: counter = flat index; fold o1^o2
__device__ __forceinline__ uint32_t pbits(uint32_t k0, uint32_t k1, uint32_t ctr) {
  U2 r = threefry(k0, k1, 0u, ctr);
  return r.a ^ r.b;
}

__device__ __forceinline__ float bits_to_unit(uint32_t bits) {
  return __uint_as_float((bits >> 9) | 0x3f800000u) - 1.0f;  // [0,1)
}

// f32 uniform(1e-6, 1-1e-6) -> gumbel, exactly jax's f32 path
__device__ __forceinline__ float jgumbel(uint32_t k0, uint32_t k1, uint32_t ctr) {
  const float minv = 1e-6f;
  const float maxv = (float)(1.0 - 1e-6);
  const float span = maxv - minv;
  float f = bits_to_unit(pbits(k0, k1, ctr));
  float u = fmaxf(minv, __fadd_rn(__fmul_rn(f, span), minv));
  return -logf(-logf(u));
}

// fp32 -> fp64 weight conversion: wd[0..16383] = w1, wd[16384..] = gat_w
extern "C" __global__ void __launch_bounds__(256)
conv_kernel(const float* __restrict__ w1, const float* __restrict__ gat_w,
            double* __restrict__ wd) {
  const int i = blockIdx.x * 256 + threadIdx.x;   // grid covers 278528 exactly
  if (i < 16384) wd[i] = (double)w1[i];
  else           wd[i] = (double)gat_w[i - 16384];
}

template<bool PRE>
__global__ __launch_bounds__(256, 4) void gen_kernel_t(
    const float* __restrict__ noise,
    const float* __restrict__ w1,
    const float* __restrict__ b1,
    const float* __restrict__ gat_w,
    const float* __restrict__ gat_b,
    const float* __restrict__ w_atom,
    const float* __restrict__ b_atom,
    const float* __restrict__ w_hyb,
    const float* __restrict__ b_hyb,
    const float* __restrict__ w_deg,
    const float* __restrict__ b_deg,
    const float* __restrict__ w_chg,
    const float* __restrict__ b_chg,
    const float* __restrict__ w_arom,
    const float* __restrict__ b_arom,
    const float* __restrict__ w_eex,
    const float* __restrict__ b_eex,
    const float* __restrict__ w_ety,
    const float* __restrict__ b_ety,
    const double* __restrict__ wd,
    float* __restrict__ out)
{
  // All LDS regions are wave-private; no block barriers anywhere.
  __shared__ __align__(16) double sX[4][128];     // x state, broadcast source
  __shared__ double sScr[4][16];                  // head logits
  __shared__ float  sNF[4][32][17];               // node features
  __shared__ double sLP[4][64];                   // lp scratch

  const int t   = threadIdx.x;
  const int wv  = t >> 6;
  const int ln  = t & 63;
  const int mol = blockIdx.x * 4 + wv;            // this wave's molecule
  const int c0  = ln << 1;                        // lane's two columns

  // ---------------- stage noise (wave-private, lockstep ordering suffices)
  {
    const float2 nz = *(const float2*)(noise + (size_t)mol * 128 + c0);
    sX[wv][c0]     = (double)nz.x;
    sX[wv][c0 + 1] = (double)nz.y;
  }

  double2 xr;   // lane's persistent register copy of x[c0], x[c0+1]

  // ---------------- phase 0: x0 = relu(noise @ w1 + b1)
  {
    double a0 = 0.0, a1 = 0.0;
    if (PRE) {
      const double* __restrict__ W = wd;
      #pragma unroll 8
      for (int k = 0; k < 128; k += 2) {
        const double2 xx = *(const double2*)&sX[wv][k];            // broadcast
        const double2 wA = *(const double2*)(W + ((size_t)k << 7) + c0);
        const double2 wB = *(const double2*)(W + ((size_t)(k + 1) << 7) + c0);
        a0 = fma(xx.x, wA.x, a0); a1 = fma(xx.x, wA.y, a1);
        a0 = fma(xx.y, wB.x, a0); a1 = fma(xx.y, wB.y, a1);
      }
    } else {
      #pragma unroll 8
      for (int k = 0; k < 128; ++k) {
        const double xk = sX[wv][k];
        const float2 w  = *(const float2*)(w1 + (k << 7) + c0);
        a0 = fma(xk, (double)w.x, a0); a1 = fma(xk, (double)w.y, a1);
      }
    }
    const float2 bb = *(const float2*)(b1 + c0);
    xr.x = fmax(a0 + (double)bb.x, 0.0);
    xr.y = fmax(a1 + (double)bb.y, 0.0);
    sX[wv][c0]     = xr.x;
    sX[wv][c0 + 1] = xr.y;
  }

  // ---------------- 16 layers: x = relu(x + x@W + b)
  for (int l = 0; l < 16; ++l) {
    double a0 = 0.0, a1 = 0.0;
    if (PRE) {
      const double* __restrict__ W = wd + 16384 + ((size_t)l << 14);
      #pragma unroll 8
      for (int k = 0; k < 128; k += 2) {
        const double2 xx = *(const double2*)&sX[wv][k];            // broadcast
        const double2 wA = *(const double2*)(W + ((size_t)k << 7) + c0);
        const double2 wB = *(const double2*)(W + ((size_t)(k + 1) << 7) + c0);
        a0 = fma(xx.x, wA.x, a0); a1 = fma(xx.x, wA.y, a1);
        a0 = fma(xx.y, wB.x, a0); a1 = fma(xx.y, wB.y, a1);
      }
    } else {
      const float* __restrict__ W = gat_w + ((size_t)l << 14);
      #pragma unroll 8
      for (int k = 0; k < 128; ++k) {
        const double xk = sX[wv][k];
        const float2 w  = *(const float2*)(W + (k << 7) + c0);
        a0 = fma(xk, (double)w.x, a0); a1 = fma(xk, (double)w.y, a1);
      }
    }
    const float2 bb = *(const float2*)(gat_b + (l << 7) + c0);
    xr.x = fmax(xr.x + a0 + (double)bb.x, 0.0);
    xr.y = fmax(xr.y + a1 + (double)bb.y, 0.0);
    sX[wv][c0]     = xr.x;
    sX[wv][c0 + 1] = xr.y;
  }

  // ---------------- phase A: 16 head logits (lanes 0..15)
  if (ln < 16) {
    const float* wp; int stride;
    if (ln < 10)       { wp = w_atom + ln;       stride = 10; }
    else if (ln < 13)  { wp = w_hyb + (ln - 10); stride = 3;  }
    else if (ln == 13) { wp = w_deg;             stride = 1;  }
    else if (ln == 14) { wp = w_chg;             stride = 1;  }
    else               { wp = w_arom;            stride = 1;  }
    double acc = 0.0;
    for (int c = 0; c < 128; ++c)
      acc = fma(sX[wv][c], (double)wp[c * stride], acc);
    double bias;
    if (ln < 10)       bias = (double)b_atom[ln];
    else if (ln < 13)  bias = (double)b_hyb[ln - 10];
    else if (ln == 13) bias = (double)b_deg[0];
    else if (ln == 14) bias = (double)b_chg[0];
    else               bias = (double)b_arom[0];
    sScr[wv][ln] = acc + bias;
  }

  // partitionable split(key(42),4): child_i = threefry((0,42),(0,i))
  const U2 k0p = threefry(0u, 42u, 0u, 0u);
  const U2 k1p = threefry(0u, 42u, 0u, 1u);
  const U2 k2p = threefry(0u, 42u, 0u, 2u);
  const U2 k3p = threefry(0u, 42u, 0u, 3u);

  // ---------------- phase B: per-node sampling (lanes 0..31 = 32 nodes)
  if (ln < 32) {
    const int n = ln;
    const double* scr = sScr[wv];         // same logits for every node

    double m = scr[0];
    #pragma unroll
    for (int a = 1; a < 10; ++a) m = fmax(m, scr[a]);
    double lsum = 0.0;
    #pragma unroll
    for (int a = 0; a < 10; ++a) lsum += exp(scr[a] - m);
    const double lse = log(lsum);
    const uint32_t abase = ((uint32_t)mol * 32u + (uint32_t)n) * 10u;
    int asel = 0; double abest = 0.0;
    #pragma unroll
    for (int a = 0; a < 10; ++a) {
      const double g = (double)jgumbel(k0p.a, k0p.b, abase + (uint32_t)a);
      const double sc = scr[a] + g;
      if (a == 0 || sc > abest) { abest = sc; asel = a; }
    }
    sLP[wv][n] = (scr[asel] - m) - lse;

    double m2 = fmax(fmax(scr[10], scr[11]), scr[12]);
    double ls2 = exp(scr[10] - m2) + exp(scr[11] - m2) + exp(scr[12] - m2);
    const double lse2 = log(ls2);
    const uint32_t hbase = ((uint32_t)mol * 32u + (uint32_t)n) * 3u;
    int hsel = 0; double hbest = 0.0;
    #pragma unroll
    for (int j = 0; j < 3; ++j) {
      const double g = (double)jgumbel(k1p.a, k1p.b, hbase + (uint32_t)j);
      const double sc = scr[10 + j] + g;
      if (j == 0 || sc > hbest) { hbest = sc; hsel = j; }
    }
    sLP[wv][32 + n] = (scr[10 + hsel] - m2) - lse2;

    const double deg = 1.0 / (1.0 + exp(-scr[13]));
    const double chg = tanh(scr[14]);
    const double pr  = 1.0 / (1.0 + exp(-scr[15]));
    const uint32_t ridx = (uint32_t)mol * 32u + (uint32_t)n;
    const double uu = (double)bits_to_unit(pbits(k2p.a, k2p.b, ridx));
    const double arom = (uu < pr) ? 1.0 : 0.0;
    const double valt[10] = {4.0/5.0, 3.0/5.0, 2.0/5.0, 1.0/5.0, 4.0/5.0,
                             2.0/5.0, 6.0/5.0, 1.0/5.0, 4.0/5.0, 4.0/5.0};
    double nf[17];
    #pragma unroll
    for (int i = 0; i < 10; ++i) nf[i] = (i == asel) ? 1.0 : 0.0;
    nf[10] = deg; nf[11] = chg;
    #pragma unroll
    for (int j = 0; j < 3; ++j) nf[12 + j] = (j == hsel) ? 1.0 : 0.0;
    nf[15] = arom; nf[16] = valt[asel];

    const size_t o = ((size_t)mol * 32 + n) * 17;
    #pragma unroll
    for (int i = 0; i < 17; ++i) {
      sNF[wv][n][i] = (float)nf[i];
      out[o + i] = (float)nf[i];
    }
  }

  // ---------------- phase C: lp means + edge heads
  {
    if (ln == 62) {
      double sa = 0.0;
      for (int n = 0; n < 32; ++n) sa += sLP[wv][n];
      out[2228224 + (size_t)mol] = (float)(sa / 32.0);
    } else if (ln == 63) {
      double sh = 0.0;
      for (int n = 0; n < 32; ++n) sh += sLP[wv][32 + n];
      out[2232320 + (size_t)mol] = (float)(sh / 32.0);
    } else {
      const int e = ln;                       // 0..61
      const int nu_ = (e < 31) ? e : (e - 30);
      const int nv_ = (e < 31) ? (e + 1) : (e - 31);
      double lex = 0.0;
      double lt[4] = {0.0, 0.0, 0.0, 0.0};
      for (int i = 0; i < 17; ++i) {
        const double f = (double)sNF[wv][nu_][i];
        lex = fma(f, (double)w_eex[i], lex);
        #pragma unroll
        for (int c = 0; c < 4; ++c) lt[c] = fma(f, (double)w_ety[i * 4 + c], lt[c]);
      }
      for (int i = 0; i < 17; ++i) {
        const double f = (double)sNF[wv][nv_][i];
        lex = fma(f, (double)w_eex[17 + i], lex);
        #pragma unroll
        for (int c = 0; c < 4; ++c) lt[c] = fma(f, (double)w_ety[(17 + i) * 4 + c], lt[c]);
      }
      lex += (double)b_eex[0];
      #pragma unroll
      for (int c = 0; c < 4; ++c) lt[c] += (double)b_ety[c];

      const double pex = 1.0 / (1.0 + exp(-lex));
      out[3252224 + (size_t)mol * 62 + e] = (pex > 0.5) ? 1.f : 0.f;

      const uint32_t tbase = ((uint32_t)mol * 62u + (uint32_t)e) * 4u;
      int tsel = 0; double tbest = 0.0;
      #pragma unroll
      for (int c = 0; c < 4; ++c) {
        const double g = (double)jgumbel(k3p.a, k3p.b, tbase + (uint32_t)c);
        const double sc = lt[c] + g;
        if (c == 0 || sc > tbest) { tbest = sc; tsel = c; }
      }
      const size_t o = 2236416 + ((size_t)mol * 62 + e) * 4;
      #pragma unroll
      for (int c = 0; c < 4; ++c) out[o + c] = (c == tsel) ? 1.f : 0.f;
    }
  }
}

extern "C" void kernel_launch(void* const* d_in, const int* in_sizes, int n_in,
                              void* d_out, int out_size, void* d_ws, size_t ws_size,
                              hipStream_t stream) {
  (void)in_sizes; (void)n_in; (void)out_size;
  const size_t need = (size_t)(16384 + 262144) * sizeof(double);   // 2.23 MB
  const bool pre = (d_ws != nullptr) && (ws_size >= need);
  if (pre) {
    hipLaunchKernelGGL(conv_kernel, dim3(1088), dim3(256), 0, stream,
                       (const float*)d_in[1], (const float*)d_in[3],
                       (double*)d_ws);
    hipLaunchKernelGGL((gen_kernel_t<true>), dim3(1024), dim3(256), 0, stream,
                       (const float*)d_in[0],  (const float*)d_in[1],
                       (const float*)d_in[2],  (const float*)d_in[3],
                       (const float*)d_in[4],
                       (const float*)d_in[7],  (const float*)d_in[8],
                       (const float*)d_in[9],  (const float*)d_in[10],
                       (const float*)d_in[11], (const float*)d_in[12],
                       (const float*)d_in[13], (const float*)d_in[14],
                       (const float*)d_in[15], (const float*)d_in[16],
                       (const float*)d_in[17], (const float*)d_in[18],
                       (const float*)d_in[19], (const float*)d_in[20],
                       (const double*)d_ws, (float*)d_out);
  } else {
    hipLaunchKernelGGL((gen_kernel_t<false>), dim3(1024), dim3(256), 0, stream,
                       (const float*)d_in[0],  (const float*)d_in[1],
                       (const float*)d_in[2],  (const float*)d_in[3],
                       (const float*)d_in[4],
                       (const float*)d_in[7],  (const float*)d_in[8],
                       (const float*)d_in[9],  (const float*)d_in[10],
                       (const float*)d_in[11], (const float*)d_in[12],
                       (const float*)d_in[13], (const float*)d_in[14],
                       (const float*)d_in[15], (const float*)d_in[16],
                       (const float*)d_in[17], (const float*)d_in[18],
                       (const float*)d_in[19], (const float*)d_in[20],
                       (const double*)nullptr, (float*)d_out);
  }
}

// Round 3
// 258.683 us; speedup vs baseline: 1.4267x; 1.4267x over previous
//
#include <hip/hip_runtime.h>
#include <stdint.h>
#include <math.h>

// ---------------------------------------------------------------------------
// Generator_44555990728950. B=4096 molecules, N=32 nodes (chain), H=128,
// 16 GAT layers. All 32 nodes of a molecule are identical through the GAT
// stack (broadcast init + attention weights sum to 1 over identical
// neighbors), so: layer = relu(x + x@W + b), one class per molecule.
// R9: M=4 molecules per wave, barrier-free, fp32 W + in-loop cvt.
//   R8 post-mortem: fp64 pre-converted W doubled VMEM bytes -> per-CU vector
//   load pipe (~64 B/cyc/CU) carried 9.1 GB -> ~235 us: load-pipe bound
//   (VALUBusy fell to 21%). Fix = amortize each W load over 4 molecules:
//   per k-iter: 1 float2 W load (8 B), 2 cvt, 2 uniform ds_read_b128
//   broadcasts of x, 8 dfma. VMEM ~29 us, VALU ~33 us, DS ~22 us.
//   1024 waves = 256 blocks = 1 block/CU, 1 wave/SIMD, zero __syncthreads().
// Deterministic pipeline fp64; JAX partitionable threefry bit-exact; outputs
// fp32. Per-node sampling / edge heads same math as R7/R8.
// ---------------------------------------------------------------------------

struct U2 { uint32_t a, b; };

// Threefry-2x32, 20 rounds, exactly as jax._src.prng
__device__ __forceinline__ U2 threefry(uint32_t k0, uint32_t k1, uint32_t x0, uint32_t x1) {
  const uint32_t ks2 = k0 ^ k1 ^ 0x1BD11BDAu;
#define TFR(r) { x0 += x1; x1 = (x1 << (r)) | (x1 >> (32 - (r))); x1 ^= x0; }
  x0 += k0;  x1 += k1;
  TFR(13) TFR(15) TFR(26) TFR(6)
  x0 += k1;  x1 += ks2 + 1u;
  TFR(17) TFR(29) TFR(16) TFR(24)
  x0 += ks2; x1 += k0 + 2u;
  TFR(13) TFR(15) TFR(26) TFR(6)
  x0 += k0;  x1 += k1 + 3u;
  TFR(17) TFR(29) TFR(16) TFR(24)
  x0 += k1;  x1 += ks2 + 4u;
  TFR(13) TFR(15) TFR(26) TFR(6)
  x0 += ks2; x1 += k0 + 5u;
#undef TFR
  U2 r; r.a = x0; r.b = x1; return r;
}

// partitionable random_bits, 32-bit: counter = flat index; fold o1^o2
__device__ __forceinline__ uint32_t pbits(uint32_t k0, uint32_t k1, uint32_t ctr) {
  U2 r = threefry(k0, k1, 0u, ctr);
  return r.a ^ r.b;
}

__device__ __forceinline__ float bits_to_unit(uint32_t bits) {
  return __uint_as_float((bits >> 9) | 0x3f800000u) - 1.0f;  // [0,1)
}

// f32 uniform(1e-6, 1-1e-6) -> gumbel, exactly jax's f32 path
__device__ __forceinline__ float jgumbel(uint32_t k0, uint32_t k1, uint32_t ctr) {
  const float minv = 1e-6f;
  const float maxv = (float)(1.0 - 1e-6);
  const float span = maxv - minv;
  float f = bits_to_unit(pbits(k0, k1, ctr));
  float u = fmaxf(minv, __fadd_rn(__fmul_rn(f, span), minv));
  return -logf(-logf(u));
}

extern "C" __global__ void __launch_bounds__(256)
gen_kernel(const float* __restrict__ noise,
           const float* __restrict__ w1,
           const float* __restrict__ b1,
           const float* __restrict__ gat_w,
           const float* __restrict__ gat_b,
           const float* __restrict__ w_atom,
           const float* __restrict__ b_atom,
           const float* __restrict__ w_hyb,
           const float* __restrict__ b_hyb,
           const float* __restrict__ w_deg,
           const float* __restrict__ b_deg,
           const float* __restrict__ w_chg,
           const float* __restrict__ b_chg,
           const float* __restrict__ w_arom,
           const float* __restrict__ b_arom,
           const float* __restrict__ w_eex,
           const float* __restrict__ b_eex,
           const float* __restrict__ w_ety,
           const float* __restrict__ b_ety,
           float* __restrict__ out)
{
  // All LDS regions are wave-private; no block barriers anywhere.
  // x layout: sXa[wv][k] = {x_m0[k], x_m1[k]}, sXb[wv][k] = {x_m2[k], x_m3[k]}
  // -> k-loop reads are uniform-address ds_read_b128 broadcasts.
  __shared__ __align__(16) double sXa[4][128][2];   // 8 KB
  __shared__ __align__(16) double sXb[4][128][2];   // 8 KB
  __shared__ double sScr[4][4][16];                 // head logits, 2 KB
  __shared__ float  sNF[4][4][32][17];              // node features, 34.8 KB
  __shared__ double sLP[4][4][64];                  // lp scratch, 8 KB

  const int t       = threadIdx.x;
  const int wv      = t >> 6;
  const int ln      = t & 63;
  const int molBase = blockIdx.x * 16 + wv * 4;     // wave owns mols molBase..+3
  const int c0      = ln << 1;                      // lane's two columns

  // ---------------- stage noise for 4 molecules (wave-private)
  {
    const float2 n0 = *(const float2*)(noise + (size_t)(molBase + 0) * 128 + c0);
    const float2 n1 = *(const float2*)(noise + (size_t)(molBase + 1) * 128 + c0);
    const float2 n2 = *(const float2*)(noise + (size_t)(molBase + 2) * 128 + c0);
    const float2 n3 = *(const float2*)(noise + (size_t)(molBase + 3) * 128 + c0);
    double2 v;
    v.x = (double)n0.x; v.y = (double)n1.x; *(double2*)&sXa[wv][c0][0]     = v;
    v.x = (double)n2.x; v.y = (double)n3.x; *(double2*)&sXb[wv][c0][0]     = v;
    v.x = (double)n0.y; v.y = (double)n1.y; *(double2*)&sXa[wv][c0 + 1][0] = v;
    v.x = (double)n2.y; v.y = (double)n3.y; *(double2*)&sXb[wv][c0 + 1][0] = v;
  }

  double2 xr0, xr1, xr2, xr3;   // persistent per-lane x[c0],x[c0+1] per mol

  // ---------------- phase 0: x0 = relu(noise @ w1 + b1)
  {
    double a0x = 0.0, a0y = 0.0, a1x = 0.0, a1y = 0.0;
    double a2x = 0.0, a2y = 0.0, a3x = 0.0, a3y = 0.0;
    #pragma unroll 8
    for (int k = 0; k < 128; ++k) {
      const double2 xab = *(const double2*)&sXa[wv][k][0];   // m0, m1 (bcast)
      const double2 xcd = *(const double2*)&sXb[wv][k][0];   // m2, m3 (bcast)
      const float2  w   = *(const float2*)(w1 + (k << 7) + c0);
      const double wx = (double)w.x, wy = (double)w.y;
      a0x = fma(xab.x, wx, a0x); a0y = fma(xab.x, wy, a0y);
      a1x = fma(xab.y, wx, a1x); a1y = fma(xab.y, wy, a1y);
      a2x = fma(xcd.x, wx, a2x); a2y = fma(xcd.x, wy, a2y);
      a3x = fma(xcd.y, wx, a3x); a3y = fma(xcd.y, wy, a3y);
    }
    const float2 bb = *(const float2*)(b1 + c0);
    const double bx = (double)bb.x, by = (double)bb.y;
    xr0.x = fmax(a0x + bx, 0.0); xr0.y = fmax(a0y + by, 0.0);
    xr1.x = fmax(a1x + bx, 0.0); xr1.y = fmax(a1y + by, 0.0);
    xr2.x = fmax(a2x + bx, 0.0); xr2.y = fmax(a2y + by, 0.0);
    xr3.x = fmax(a3x + bx, 0.0); xr3.y = fmax(a3y + by, 0.0);
    double2 v;
    v.x = xr0.x; v.y = xr1.x; *(double2*)&sXa[wv][c0][0]     = v;
    v.x = xr2.x; v.y = xr3.x; *(double2*)&sXb[wv][c0][0]     = v;
    v.x = xr0.y; v.y = xr1.y; *(double2*)&sXa[wv][c0 + 1][0] = v;
    v.x = xr2.y; v.y = xr3.y; *(double2*)&sXb[wv][c0 + 1][0] = v;
  }

  // ---------------- 16 layers: x = relu(x + x@W + b)
  for (int l = 0; l < 16; ++l) {
    const float* __restrict__ W = gat_w + ((size_t)l << 14);
    double a0x = 0.0, a0y = 0.0, a1x = 0.0, a1y = 0.0;
    double a2x = 0.0, a2y = 0.0, a3x = 0.0, a3y = 0.0;
    #pragma unroll 8
    for (int k = 0; k < 128; ++k) {
      const double2 xab = *(const double2*)&sXa[wv][k][0];
      const double2 xcd = *(const double2*)&sXb[wv][k][0];
      const float2  w   = *(const float2*)(W + (k << 7) + c0);
      const double wx = (double)w.x, wy = (double)w.y;
      a0x = fma(xab.x, wx, a0x); a0y = fma(xab.x, wy, a0y);
      a1x = fma(xab.y, wx, a1x); a1y = fma(xab.y, wy, a1y);
      a2x = fma(xcd.x, wx, a2x); a2y = fma(xcd.x, wy, a2y);
      a3x = fma(xcd.y, wx, a3x); a3y = fma(xcd.y, wy, a3y);
    }
    const float2 bb = *(const float2*)(gat_b + (l << 7) + c0);
    const double bx = (double)bb.x, by = (double)bb.y;
    xr0.x = fmax(xr0.x + a0x + bx, 0.0); xr0.y = fmax(xr0.y + a0y + by, 0.0);
    xr1.x = fmax(xr1.x + a1x + bx, 0.0); xr1.y = fmax(xr1.y + a1y + by, 0.0);
    xr2.x = fmax(xr2.x + a2x + bx, 0.0); xr2.y = fmax(xr2.y + a2y + by, 0.0);
    xr3.x = fmax(xr3.x + a3x + bx, 0.0); xr3.y = fmax(xr3.y + a3y + by, 0.0);
    double2 v;
    v.x = xr0.x; v.y = xr1.x; *(double2*)&sXa[wv][c0][0]     = v;
    v.x = xr2.x; v.y = xr3.x; *(double2*)&sXb[wv][c0][0]     = v;
    v.x = xr0.y; v.y = xr1.y; *(double2*)&sXa[wv][c0 + 1][0] = v;
    v.x = xr2.y; v.y = xr3.y; *(double2*)&sXb[wv][c0 + 1][0] = v;
  }

  // ---------------- phase A: head logits, all 64 lanes = 4 mols x 16 heads
  {
    const int mloc = ln >> 4;          // 0..3
    const int h    = ln & 15;          // head index
    const double* xsrc = (mloc < 2) ? &sXa[wv][0][mloc] : &sXb[wv][0][mloc - 2];
    const float* wp; int stride; double bias;
    if (h < 10)       { wp = w_atom + h;        stride = 10; bias = (double)b_atom[h]; }
    else if (h < 13)  { wp = w_hyb + (h - 10);  stride = 3;  bias = (double)b_hyb[h - 10]; }
    else if (h == 13) { wp = w_deg;             stride = 1;  bias = (double)b_deg[0]; }
    else if (h == 14) { wp = w_chg;             stride = 1;  bias = (double)b_chg[0]; }
    else              { wp = w_arom;            stride = 1;  bias = (double)b_arom[0]; }
    double acc = 0.0;
    for (int c = 0; c < 128; ++c)
      acc = fma(xsrc[(size_t)c * 2], (double)wp[c * stride], acc);
    sScr[wv][mloc][h] = acc + bias;
  }

  // partitionable split(key(42),4): child_i = threefry((0,42),(0,i))
  const U2 k0p = threefry(0u, 42u, 0u, 0u);
  const U2 k1p = threefry(0u, 42u, 0u, 1u);
  const U2 k2p = threefry(0u, 42u, 0u, 2u);
  const U2 k3p = threefry(0u, 42u, 0u, 3u);

  // ---------------- phase B: per-node sampling, 2 rounds of (2 mols x 32 nodes)
  for (int r = 0; r < 2; ++r) {
    const int mloc = r * 2 + (ln >> 5);
    const int n    = ln & 31;
    const int mol  = molBase + mloc;
    const double* scr = sScr[wv][mloc];   // same logits for every node

    double m = scr[0];
    #pragma unroll
    for (int a = 1; a < 10; ++a) m = fmax(m, scr[a]);
    double lsum = 0.0;
    #pragma unroll
    for (int a = 0; a < 10; ++a) lsum += exp(scr[a] - m);
    const double lse = log(lsum);
    const uint32_t abase = ((uint32_t)mol * 32u + (uint32_t)n) * 10u;
    int asel = 0; double abest = 0.0;
    #pragma unroll
    for (int a = 0; a < 10; ++a) {
      const double g = (double)jgumbel(k0p.a, k0p.b, abase + (uint32_t)a);
      const double sc = scr[a] + g;
      if (a == 0 || sc > abest) { abest = sc; asel = a; }
    }
    sLP[wv][mloc][n] = (scr[asel] - m) - lse;

    double m2 = fmax(fmax(scr[10], scr[11]), scr[12]);
    double ls2 = exp(scr[10] - m2) + exp(scr[11] - m2) + exp(scr[12] - m2);
    const double lse2 = log(ls2);
    const uint32_t hbase = ((uint32_t)mol * 32u + (uint32_t)n) * 3u;
    int hsel = 0; double hbest = 0.0;
    #pragma unroll
    for (int j = 0; j < 3; ++j) {
      const double g = (double)jgumbel(k1p.a, k1p.b, hbase + (uint32_t)j);
      const double sc = scr[10 + j] + g;
      if (j == 0 || sc > hbest) { hbest = sc; hsel = j; }
    }
    sLP[wv][mloc][32 + n] = (scr[10 + hsel] - m2) - lse2;

    const double deg = 1.0 / (1.0 + exp(-scr[13]));
    const double chg = tanh(scr[14]);
    const double pr  = 1.0 / (1.0 + exp(-scr[15]));
    const uint32_t ridx = (uint32_t)mol * 32u + (uint32_t)n;
    const double uu = (double)bits_to_unit(pbits(k2p.a, k2p.b, ridx));
    const double arom = (uu < pr) ? 1.0 : 0.0;
    const double valt[10] = {4.0/5.0, 3.0/5.0, 2.0/5.0, 1.0/5.0, 4.0/5.0,
                             2.0/5.0, 6.0/5.0, 1.0/5.0, 4.0/5.0, 4.0/5.0};
    double nf[17];
    #pragma unroll
    for (int i = 0; i < 10; ++i) nf[i] = (i == asel) ? 1.0 : 0.0;
    nf[10] = deg; nf[11] = chg;
    #pragma unroll
    for (int j = 0; j < 3; ++j) nf[12 + j] = (j == hsel) ? 1.0 : 0.0;
    nf[15] = arom; nf[16] = valt[asel];

    const size_t o = ((size_t)mol * 32 + n) * 17;
    #pragma unroll
    for (int i = 0; i < 17; ++i) {
      sNF[wv][mloc][n][i] = (float)nf[i];
      out[o + i] = (float)nf[i];
    }
  }

  // ---------------- phase C: lp means + edge heads, 4 mols sequentially
  #pragma unroll 1
  for (int m = 0; m < 4; ++m) {
    const int mol = molBase + m;
    if (ln == 62) {
      double sa = 0.0;
      for (int n = 0; n < 32; ++n) sa += sLP[wv][m][n];
      out[2228224 + (size_t)mol] = (float)(sa / 32.0);
    } else if (ln == 63) {
      double sh = 0.0;
      for (int n = 0; n < 32; ++n) sh += sLP[wv][m][32 + n];
      out[2232320 + (size_t)mol] = (float)(sh / 32.0);
    } else {
      const int e = ln;                       // 0..61
      const int nu_ = (e < 31) ? e : (e - 30);
      const int nv_ = (e < 31) ? (e + 1) : (e - 31);
      double lex = 0.0;
      double lt[4] = {0.0, 0.0, 0.0, 0.0};
      for (int i = 0; i < 17; ++i) {
        const double f = (double)sNF[wv][m][nu_][i];
        lex = fma(f, (double)w_eex[i], lex);
        #pragma unroll
        for (int c = 0; c < 4; ++c) lt[c] = fma(f, (double)w_ety[i * 4 + c], lt[c]);
      }
      for (int i = 0; i < 17; ++i) {
        const double f = (double)sNF[wv][m][nv_][i];
        lex = fma(f, (double)w_eex[17 + i], lex);
        #pragma unroll
        for (int c = 0; c < 4; ++c) lt[c] = fma(f, (double)w_ety[(17 + i) * 4 + c], lt[c]);
      }
      lex += (double)b_eex[0];
      #pragma unroll
      for (int c = 0; c < 4; ++c) lt[c] += (double)b_ety[c];

      const double pex = 1.0 / (1.0 + exp(-lex));
      out[3252224 + (size_t)mol * 62 + e] = (pex > 0.5) ? 1.f : 0.f;

      const uint32_t tbase = ((uint32_t)mol * 62u + (uint32_t)e) * 4u;
      int tsel = 0; double tbest = 0.0;
      #pragma unroll
      for (int c = 0; c < 4; ++c) {
        const double g = (double)jgumbel(k3p.a, k3p.b, tbase + (uint32_t)c);
        const double sc = lt[c] + g;
        if (c == 0 || sc > tbest) { tbest = sc; tsel = c; }
      }
      const size_t o = 2236416 + ((size_t)mol * 62 + e) * 4;
      #pragma unroll
      for (int c = 0; c < 4; ++c) out[o + c] = (c == tsel) ? 1.f : 0.f;
    }
  }
}

extern "C" void kernel_launch(void* const* d_in, const int* in_sizes, int n_in,
                              void* d_out, int out_size, void* d_ws, size_t ws_size,
                              hipStream_t stream) {
  (void)in_sizes; (void)n_in; (void)out_size; (void)d_ws; (void)ws_size;
  hipLaunchKernelGGL(gen_kernel, dim3(256), dim3(256), 0, stream,
                     (const float*)d_in[0],  (const float*)d_in[1],
                     (const float*)d_in[2],  (const float*)d_in[3],
                     (const float*)d_in[4],
                     (const float*)d_in[7],  (const float*)d_in[8],
                     (const float*)d_in[9],  (const float*)d_in[10],
                     (const float*)d_in[11], (const float*)d_in[12],
                     (const float*)d_in[13], (const float*)d_in[14],
                     (const float*)d_in[15], (const float*)d_in[16],
                     (const float*)d_in[17], (const float*)d_in[18],
                     (const float*)d_in[19], (const float*)d_in[20],
                     (float*)d_out);
}

// Round 4
// 203.396 us; speedup vs baseline: 1.8145x; 1.2718x over previous
//
#include <hip/hip_runtime.h>
#include <stdint.h>
#include <math.h>

// ---------------------------------------------------------------------------
// Generator_44555990728950. B=4096 molecules, N=32 nodes (chain), H=128,
// 16 GAT layers. All 32 nodes of a molecule are identical through the GAT
// stack (broadcast init + attention weights sum to 1 over identical
// neighbors), so: layer = relu(x + x@W + b), one class per molecule.
// R10: M=4 per wave, barrier-free (R9 structure) + MANUAL SOFTWARE PIPELINE.
//   R9 post-mortem: 209 cyc/iter = one exposed L2 latency per k-iteration;
//   compiler did not pipeline (VGPR=88). At 1 wave/SIMD only ILP hides
//   latency -> explicit double-buffered chunks of 8 k-iters in registers:
//   issue chunk c+1's 8 W float2 loads + 16 ds_read_b128 x-broadcasts while
//   computing chunk c (~350 cyc of dfma) -> covers ~200-300 cyc L2 latency.
//   All buffer indices compile-time (full unroll) -> stays in VGPRs (~210).
//   Layer 0 (w1/b1, no residual) unified into the 17-layer loop.
// Deterministic pipeline fp64 (accumulation order unchanged vs R9);
// JAX partitionable threefry bit-exact; outputs fp32.
// ---------------------------------------------------------------------------

struct U2 { uint32_t a, b; };

// Threefry-2x32, 20 rounds, exactly as jax._src.prng
__device__ __forceinline__ U2 threefry(uint32_t k0, uint32_t k1, uint32_t x0, uint32_t x1) {
  const uint32_t ks2 = k0 ^ k1 ^ 0x1BD11BDAu;
#define TFR(r) { x0 += x1; x1 = (x1 << (r)) | (x1 >> (32 - (r))); x1 ^= x0; }
  x0 += k0;  x1 += k1;
  TFR(13) TFR(15) TFR(26) TFR(6)
  x0 += k1;  x1 += ks2 + 1u;
  TFR(17) TFR(29) TFR(16) TFR(24)
  x0 += ks2; x1 += k0 + 2u;
  TFR(13) TFR(15) TFR(26) TFR(6)
  x0 += k0;  x1 += k1 + 3u;
  TFR(17) TFR(29) TFR(16) TFR(24)
  x0 += k1;  x1 += ks2 + 4u;
  TFR(13) TFR(15) TFR(26) TFR(6)
  x0 += ks2; x1 += k0 + 5u;
#undef TFR
  U2 r; r.a = x0; r.b = x1; return r;
}

// partitionable random_bits, 32-bit: counter = flat index; fold o1^o2
__device__ __forceinline__ uint32_t pbits(uint32_t k0, uint32_t k1, uint32_t ctr) {
  U2 r = threefry(k0, k1, 0u, ctr);
  return r.a ^ r.b;
}

__device__ __forceinline__ float bits_to_unit(uint32_t bits) {
  return __uint_as_float((bits >> 9) | 0x3f800000u) - 1.0f;  // [0,1)
}

// f32 uniform(1e-6, 1-1e-6) -> gumbel, exactly jax's f32 path
__device__ __forceinline__ float jgumbel(uint32_t k0, uint32_t k1, uint32_t ctr) {
  const float minv = 1e-6f;
  const float maxv = (float)(1.0 - 1e-6);
  const float span = maxv - minv;
  float f = bits_to_unit(pbits(k0, k1, ctr));
  float u = fmaxf(minv, __fadd_rn(__fmul_rn(f, span), minv));
  return -logf(-logf(u));
}

extern "C" __global__ void __launch_bounds__(256)
gen_kernel(const float* __restrict__ noise,
           const float* __restrict__ w1,
           const float* __restrict__ b1,
           const float* __restrict__ gat_w,
           const float* __restrict__ gat_b,
           const float* __restrict__ w_atom,
           const float* __restrict__ b_atom,
           const float* __restrict__ w_hyb,
           const float* __restrict__ b_hyb,
           const float* __restrict__ w_deg,
           const float* __restrict__ b_deg,
           const float* __restrict__ w_chg,
           const float* __restrict__ b_chg,
           const float* __restrict__ w_arom,
           const float* __restrict__ b_arom,
           const float* __restrict__ w_eex,
           const float* __restrict__ b_eex,
           const float* __restrict__ w_ety,
           const float* __restrict__ b_ety,
           float* __restrict__ out)
{
  // All LDS regions are wave-private; no block barriers anywhere.
  // x layout: sXa[wv][k] = {x_m0[k], x_m1[k]}, sXb[wv][k] = {x_m2[k], x_m3[k]}
  // -> k-loop reads are uniform-address ds_read_b128 broadcasts.
  __shared__ __align__(16) double sXa[4][128][2];   // 8 KB
  __shared__ __align__(16) double sXb[4][128][2];   // 8 KB
  __shared__ double sScr[4][4][16];                 // head logits, 2 KB
  __shared__ float  sNF[4][4][32][17];              // node features, 34.8 KB
  __shared__ double sLP[4][4][64];                  // lp scratch, 8 KB

  const int t       = threadIdx.x;
  const int wv      = t >> 6;
  const int ln      = t & 63;
  const int molBase = blockIdx.x * 16 + wv * 4;     // wave owns mols molBase..+3
  const int c0      = ln << 1;                      // lane's two columns

  // ---------------- stage noise for 4 molecules (wave-private)
  {
    const float2 n0 = *(const float2*)(noise + (size_t)(molBase + 0) * 128 + c0);
    const float2 n1 = *(const float2*)(noise + (size_t)(molBase + 1) * 128 + c0);
    const float2 n2 = *(const float2*)(noise + (size_t)(molBase + 2) * 128 + c0);
    const float2 n3 = *(const float2*)(noise + (size_t)(molBase + 3) * 128 + c0);
    double2 v;
    v.x = (double)n0.x; v.y = (double)n1.x; *(double2*)&sXa[wv][c0][0]     = v;
    v.x = (double)n2.x; v.y = (double)n3.x; *(double2*)&sXb[wv][c0][0]     = v;
    v.x = (double)n0.y; v.y = (double)n1.y; *(double2*)&sXa[wv][c0 + 1][0] = v;
    v.x = (double)n2.y; v.y = (double)n3.y; *(double2*)&sXb[wv][c0 + 1][0] = v;
  }

  double2 xr0, xr1, xr2, xr3;   // persistent per-lane x[c0],x[c0+1] per mol

  // ---------------- 17 unified layers:
  //   l==0 : x = relu(noise @ w1 + b1)
  //   l>=1 : x = relu(x + x@W_l + b_l)
  // Manual 2-stage software pipeline, chunks of 8 k-iterations.
  #pragma unroll 1
  for (int l = 0; l < 17; ++l) {
    const float* __restrict__ W  = (l == 0) ? w1 : (gat_w + (((size_t)(l - 1)) << 14));
    const float* __restrict__ bp = (l == 0) ? b1 : (gat_b + ((l - 1) << 7));

    double a0x = 0.0, a0y = 0.0, a1x = 0.0, a1y = 0.0;
    double a2x = 0.0, a2y = 0.0, a3x = 0.0, a3y = 0.0;

    float2  wA[8];  double2 xaA[8], xbA[8];
    float2  wB[8];  double2 xaB[8], xbB[8];

    // prologue: chunk 0 -> buffer A
    #pragma unroll
    for (int j = 0; j < 8; ++j) {
      wA[j]  = *(const float2*)(W + (j << 7) + c0);
      xaA[j] = *(const double2*)&sXa[wv][j][0];
      xbA[j] = *(const double2*)&sXb[wv][j][0];
    }

    #pragma unroll
    for (int ch = 0; ch < 16; ++ch) {
      const int nb = (ch + 1) << 3;                 // next chunk base
      if ((ch & 1) == 0) {
        if (ch < 15) {
          #pragma unroll
          for (int j = 0; j < 8; ++j) {
            wB[j]  = *(const float2*)(W + ((nb + j) << 7) + c0);
            xaB[j] = *(const double2*)&sXa[wv][nb + j][0];
            xbB[j] = *(const double2*)&sXb[wv][nb + j][0];
          }
        }
        #pragma unroll
        for (int j = 0; j < 8; ++j) {
          const double wx = (double)wA[j].x, wy = (double)wA[j].y;
          a0x = fma(xaA[j].x, wx, a0x); a0y = fma(xaA[j].x, wy, a0y);
          a1x = fma(xaA[j].y, wx, a1x); a1y = fma(xaA[j].y, wy, a1y);
          a2x = fma(xbA[j].x, wx, a2x); a2y = fma(xbA[j].x, wy, a2y);
          a3x = fma(xbA[j].y, wx, a3x); a3y = fma(xbA[j].y, wy, a3y);
        }
      } else {
        if (ch < 15) {
          #pragma unroll
          for (int j = 0; j < 8; ++j) {
            wA[j]  = *(const float2*)(W + ((nb + j) << 7) + c0);
            xaA[j] = *(const double2*)&sXa[wv][nb + j][0];
            xbA[j] = *(const double2*)&sXb[wv][nb + j][0];
          }
        }
        #pragma unroll
        for (int j = 0; j < 8; ++j) {
          const double wx = (double)wB[j].x, wy = (double)wB[j].y;
          a0x = fma(xaB[j].x, wx, a0x); a0y = fma(xaB[j].x, wy, a0y);
          a1x = fma(xaB[j].y, wx, a1x); a1y = fma(xaB[j].y, wy, a1y);
          a2x = fma(xbB[j].x, wx, a2x); a2y = fma(xbB[j].x, wy, a2y);
          a3x = fma(xbB[j].y, wx, a3x); a3y = fma(xbB[j].y, wy, a3y);
        }
      }
    }

    const float2 bb = *(const float2*)(bp + c0);
    const double bx = (double)bb.x, by = (double)bb.y;
    if (l == 0) {
      xr0.x = fmax(a0x + bx, 0.0); xr0.y = fmax(a0y + by, 0.0);
      xr1.x = fmax(a1x + bx, 0.0); xr1.y = fmax(a1y + by, 0.0);
      xr2.x = fmax(a2x + bx, 0.0); xr2.y = fmax(a2y + by, 0.0);
      xr3.x = fmax(a3x + bx, 0.0); xr3.y = fmax(a3y + by, 0.0);
    } else {
      xr0.x = fmax(xr0.x + a0x + bx, 0.0); xr0.y = fmax(xr0.y + a0y + by, 0.0);
      xr1.x = fmax(xr1.x + a1x + bx, 0.0); xr1.y = fmax(xr1.y + a1y + by, 0.0);
      xr2.x = fmax(xr2.x + a2x + bx, 0.0); xr2.y = fmax(xr2.y + a2y + by, 0.0);
      xr3.x = fmax(xr3.x + a3x + bx, 0.0); xr3.y = fmax(xr3.y + a3y + by, 0.0);
    }
    double2 v;
    v.x = xr0.x; v.y = xr1.x; *(double2*)&sXa[wv][c0][0]     = v;
    v.x = xr2.x; v.y = xr3.x; *(double2*)&sXb[wv][c0][0]     = v;
    v.x = xr0.y; v.y = xr1.y; *(double2*)&sXa[wv][c0 + 1][0] = v;
    v.x = xr2.y; v.y = xr3.y; *(double2*)&sXb[wv][c0 + 1][0] = v;
  }

  // ---------------- phase A: head logits, all 64 lanes = 4 mols x 16 heads
  {
    const int mloc = ln >> 4;          // 0..3
    const int h    = ln & 15;          // head index
    const double* xsrc = (mloc < 2) ? &sXa[wv][0][mloc] : &sXb[wv][0][mloc - 2];
    const float* wp; int stride; double bias;
    if (h < 10)       { wp = w_atom + h;        stride = 10; bias = (double)b_atom[h]; }
    else if (h < 13)  { wp = w_hyb + (h - 10);  stride = 3;  bias = (double)b_hyb[h - 10]; }
    else if (h == 13) { wp = w_deg;             stride = 1;  bias = (double)b_deg[0]; }
    else if (h == 14) { wp = w_chg;             stride = 1;  bias = (double)b_chg[0]; }
    else              { wp = w_arom;            stride = 1;  bias = (double)b_arom[0]; }
    double acc = 0.0;
    for (int c = 0; c < 128; ++c)
      acc = fma(xsrc[(size_t)c * 2], (double)wp[c * stride], acc);
    sScr[wv][mloc][h] = acc + bias;
  }

  // partitionable split(key(42),4): child_i = threefry((0,42),(0,i))
  const U2 k0p = threefry(0u, 42u, 0u, 0u);
  const U2 k1p = threefry(0u, 42u, 0u, 1u);
  const U2 k2p = threefry(0u, 42u, 0u, 2u);
  const U2 k3p = threefry(0u, 42u, 0u, 3u);

  // ---------------- phase B: per-node sampling, 2 rounds of (2 mols x 32 nodes)
  for (int r = 0; r < 2; ++r) {
    const int mloc = r * 2 + (ln >> 5);
    const int n    = ln & 31;
    const int mol  = molBase + mloc;
    const double* scr = sScr[wv][mloc];   // same logits for every node

    double m = scr[0];
    #pragma unroll
    for (int a = 1; a < 10; ++a) m = fmax(m, scr[a]);
    double lsum = 0.0;
    #pragma unroll
    for (int a = 0; a < 10; ++a) lsum += exp(scr[a] - m);
    const double lse = log(lsum);
    const uint32_t abase = ((uint32_t)mol * 32u + (uint32_t)n) * 10u;
    int asel = 0; double abest = 0.0;
    #pragma unroll
    for (int a = 0; a < 10; ++a) {
      const double g = (double)jgumbel(k0p.a, k0p.b, abase + (uint32_t)a);
      const double sc = scr[a] + g;
      if (a == 0 || sc > abest) { abest = sc; asel = a; }
    }
    sLP[wv][mloc][n] = (scr[asel] - m) - lse;

    double m2 = fmax(fmax(scr[10], scr[11]), scr[12]);
    double ls2 = exp(scr[10] - m2) + exp(scr[11] - m2) + exp(scr[12] - m2);
    const double lse2 = log(ls2);
    const uint32_t hbase = ((uint32_t)mol * 32u + (uint32_t)n) * 3u;
    int hsel = 0; double hbest = 0.0;
    #pragma unroll
    for (int j = 0; j < 3; ++j) {
      const double g = (double)jgumbel(k1p.a, k1p.b, hbase + (uint32_t)j);
      const double sc = scr[10 + j] + g;
      if (j == 0 || sc > hbest) { hbest = sc; hsel = j; }
    }
    sLP[wv][mloc][32 + n] = (scr[10 + hsel] - m2) - lse2;

    const double deg = 1.0 / (1.0 + exp(-scr[13]));
    const double chg = tanh(scr[14]);
    const double pr  = 1.0 / (1.0 + exp(-scr[15]));
    const uint32_t ridx = (uint32_t)mol * 32u + (uint32_t)n;
    const double uu = (double)bits_to_unit(pbits(k2p.a, k2p.b, ridx));
    const double arom = (uu < pr) ? 1.0 : 0.0;
    const double valt[10] = {4.0/5.0, 3.0/5.0, 2.0/5.0, 1.0/5.0, 4.0/5.0,
                             2.0/5.0, 6.0/5.0, 1.0/5.0, 4.0/5.0, 4.0/5.0};
    double nf[17];
    #pragma unroll
    for (int i = 0; i < 10; ++i) nf[i] = (i == asel) ? 1.0 : 0.0;
    nf[10] = deg; nf[11] = chg;
    #pragma unroll
    for (int j = 0; j < 3; ++j) nf[12 + j] = (j == hsel) ? 1.0 : 0.0;
    nf[15] = arom; nf[16] = valt[asel];

    const size_t o = ((size_t)mol * 32 + n) * 17;
    #pragma unroll
    for (int i = 0; i < 17; ++i) {
      sNF[wv][mloc][n][i] = (float)nf[i];
      out[o + i] = (float)nf[i];
    }
  }

  // ---------------- phase C: lp means + edge heads, 4 mols sequentially
  #pragma unroll 1
  for (int m = 0; m < 4; ++m) {
    const int mol = molBase + m;
    if (ln == 62) {
      double sa = 0.0;
      for (int n = 0; n < 32; ++n) sa += sLP[wv][m][n];
      out[2228224 + (size_t)mol] = (float)(sa / 32.0);
    } else if (ln == 63) {
      double sh = 0.0;
      for (int n = 0; n < 32; ++n) sh += sLP[wv][m][32 + n];
      out[2232320 + (size_t)mol] = (float)(sh / 32.0);
    } else {
      const int e = ln;                       // 0..61
      const int nu_ = (e < 31) ? e : (e - 30);
      const int nv_ = (e < 31) ? (e + 1) : (e - 31);
      double lex = 0.0;
      double lt[4] = {0.0, 0.0, 0.0, 0.0};
      for (int i = 0; i < 17; ++i) {
        const double f = (double)sNF[wv][m][nu_][i];
        lex = fma(f, (double)w_eex[i], lex);
        #pragma unroll
        for (int c = 0; c < 4; ++c) lt[c] = fma(f, (double)w_ety[i * 4 + c], lt[c]);
      }
      for (int i = 0; i < 17; ++i) {
        const double f = (double)sNF[wv][m][nv_][i];
        lex = fma(f, (double)w_eex[17 + i], lex);
        #pragma unroll
        for (int c = 0; c < 4; ++c) lt[c] = fma(f, (double)w_ety[(17 + i) * 4 + c], lt[c]);
      }
      lex += (double)b_eex[0];
      #pragma unroll
      for (int c = 0; c < 4; ++c) lt[c] += (double)b_ety[c];

      const double pex = 1.0 / (1.0 + exp(-lex));
      out[3252224 + (size_t)mol * 62 + e] = (pex > 0.5) ? 1.f : 0.f;

      const uint32_t tbase = ((uint32_t)mol * 62u + (uint32_t)e) * 4u;
      int tsel = 0; double tbest = 0.0;
      #pragma unroll
      for (int c = 0; c < 4; ++c) {
        const double g = (double)jgumbel(k3p.a, k3p.b, tbase + (uint32_t)c);
        const double sc = lt[c] + g;
        if (c == 0 || sc > tbest) { tbest = sc; tsel = c; }
      }
      const size_t o = 2236416 + ((size_t)mol * 62 + e) * 4;
      #pragma unroll
      for (int c = 0; c < 4; ++c) out[o + c] = (c == tsel) ? 1.f : 0.f;
    }
  }
}

extern "C" void kernel_launch(void* const* d_in, const int* in_sizes, int n_in,
                              void* d_out, int out_size, void* d_ws, size_t ws_size,
                              hipStream_t stream) {
  (void)in_sizes; (void)n_in; (void)out_size; (void)d_ws; (void)ws_size;
  hipLaunchKernelGGL(gen_kernel, dim3(256), dim3(256), 0, stream,
                     (const float*)d_in[0],  (const float*)d_in[1],
                     (const float*)d_in[2],  (const float*)d_in[3],
                     (const float*)d_in[4],
                     (const float*)d_in[7],  (const float*)d_in[8],
                     (const float*)d_in[9],  (const float*)d_in[10],
                     (const float*)d_in[11], (const float*)d_in[12],
                     (const float*)d_in[13], (const float*)d_in[14],
                     (const float*)d_in[15], (const float*)d_in[16],
                     (const float*)d_in[17], (const float*)d_in[18],
                     (const float*)d_in[19], (const float*)d_in[20],
                     (float*)d_out);
}